// Round 4
// baseline (7850.185 us; speedup 1.0000x reference)
//
#include <hip/hip_runtime.h>

typedef unsigned short ushort;
typedef __attribute__((ext_vector_type(8))) short short8;
typedef __attribute__((ext_vector_type(4))) float f32x4;
typedef __attribute__((ext_vector_type(4))) unsigned short us4;

// Problem constants
#define BB 32
#define TT 512
#define DIN 512
#define HH 1024
#define CHUNK 128   // time steps per chunk (4 chunks)

__device__ __forceinline__ ushort f2b(float f) {
  unsigned u = __builtin_bit_cast(unsigned, f);
  unsigned r = (u + 0x7fffu + ((u >> 16) & 1u)) >> 16;
  return (ushort)r;
}

#define MFMA16(a, b, c) __builtin_amdgcn_mfma_f32_16x16x32_bf16(a, b, c, 0, 0, 0)

// ---------------------------------------------------------------- init
// zero h1 slot0, h2 slot0, flags (2 x 128)
__global__ __launch_bounds__(256) void init_k(unsigned int* h1s, unsigned int* h2s,
                                              int* f0, int* f1) {
  int i = blockIdx.x * 256 + threadIdx.x;   // grid 128 -> 32768 threads
  if (i < 16384) h1s[i] = 0u;
  else h2s[i - 16384] = 0u;
  if (i < 128) f0[i] = 0;
  else if (i < 256) f1[i - 128] = 0;
}

// ---------------------------------------------------------------- fp32 -> bf16 cast
__global__ __launch_bounds__(256) void cast_k(const float* __restrict__ in,
                                              ushort* __restrict__ out, int n4) {
  int i = blockIdx.x * 256 + threadIdx.x;
  if (i < n4) {
    float4 v = ((const float4*)in)[i];
    us4 o;
    o.x = f2b(v.x); o.y = f2b(v.y); o.z = f2b(v.z); o.w = f2b(v.w);
    ((us4*)out)[i] = o;
  }
}

// ---------------------------------------------------------------- bf16 GEMM  C = A @ B^T
// M = 4096 (128 steps x 32 batch, t-major), N = 3072.
// AF32=1: A is fp32 x [B,T,DIN], row m -> x[(m&31)*TT + tOff + (m>>5)], cast on the fly.
template <int AF32>
__global__ __launch_bounds__(256) void gemm_bt(const void* __restrict__ Ap,
                                               const ushort* __restrict__ B,
                                               float* __restrict__ C,
                                               int N, int K, int tOff) {
  __shared__ __align__(16) ushort As[128 * 72];
  __shared__ __align__(16) ushort Bs[128 * 72];
  const int tid = threadIdx.x;
  const int lane = tid & 63, wave = tid >> 6;
  const int wm = wave >> 1, wn = wave & 1;
  const int bm = blockIdx.y << 7, bn = blockIdx.x << 7;

  const int srow = tid >> 3;
  const int sdst = (tid & 7) << 3;
  size_t aoff[4], boff[4];
#pragma unroll
  for (int i = 0; i < 4; ++i) {
    int m = bm + srow + (i << 5);
    if (AF32) aoff[i] = ((size_t)(m & 31) * TT + tOff + (m >> 5)) * (size_t)K;
    else      aoff[i] = (size_t)m * K;
    boff[i] = (size_t)(bn + srow + (i << 5)) * K;
  }

  const int fr = lane & 15, fq = lane >> 4;
  int aofl[4], bofl[4];
#pragma unroll
  for (int m = 0; m < 4; ++m) {
    aofl[m] = ((wm << 6) + (m << 4) + fr) * 72 + (fq << 3);
    bofl[m] = ((wn << 6) + (m << 4) + fr) * 72 + (fq << 3);
  }

  f32x4 acc[4][4] = {};
  for (int k0 = 0; k0 < K; k0 += 64) {
#pragma unroll
    for (int i = 0; i < 4; ++i) {
      int row = srow + (i << 5);
      if (AF32) {
        const float* A32 = (const float*)Ap;
        float4 v0 = *(const float4*)&A32[aoff[i] + k0 + sdst];
        float4 v1 = *(const float4*)&A32[aoff[i] + k0 + sdst + 4];
        us4 lo, hi;
        lo.x = f2b(v0.x); lo.y = f2b(v0.y); lo.z = f2b(v0.z); lo.w = f2b(v0.w);
        hi.x = f2b(v1.x); hi.y = f2b(v1.y); hi.z = f2b(v1.z); hi.w = f2b(v1.w);
        *(us4*)&As[row * 72 + sdst] = lo;
        *(us4*)&As[row * 72 + sdst + 4] = hi;
      } else {
        *(short8*)&As[row * 72 + sdst] = *(const short8*)&((const ushort*)Ap)[aoff[i] + k0 + sdst];
      }
      *(short8*)&Bs[row * 72 + sdst] = *(const short8*)&B[boff[i] + k0 + sdst];
    }
    __syncthreads();
#pragma unroll
    for (int kk = 0; kk < 2; ++kk) {
      short8 af[4], bf[4];
#pragma unroll
      for (int m = 0; m < 4; ++m) af[m] = *(const short8*)&As[aofl[m] + kk * 32];
#pragma unroll
      for (int n = 0; n < 4; ++n) bf[n] = *(const short8*)&Bs[bofl[n] + kk * 32];
#pragma unroll
      for (int m = 0; m < 4; ++m)
#pragma unroll
        for (int n = 0; n < 4; ++n)
          acc[m][n] = MFMA16(af[m], bf[n], acc[m][n]);
    }
    __syncthreads();
  }
#pragma unroll
  for (int m = 0; m < 4; ++m) {
    int row0 = bm + (wm << 6) + (m << 4) + (fq << 2);
#pragma unroll
    for (int n = 0; n < 4; ++n) {
      int col = bn + (wn << 6) + (n << 4) + fr;
#pragma unroll
      for (int r = 0; r < 4; ++r)
        C[(size_t)(row0 + r) * N + col] = acc[m][n][r];
    }
  }
}

// ---------------------------------------------------------------- persistent GRU layer
// 64 WGs x 256 thr (4 waves). WG owns h-cols [16*wg, 16*wg+16).
// K-split: wave w covers K in [256w, 256w+256). W_hh frags live in VGPRs (96/lane),
// h[t] frags load global->register (L3). Partials cross-wave reduced via LDS
// (transposed, conflict-free, double-buffered). Waves 0/1 compute gates for their
// 16-batch half and publish via agent-atomic stores + vmcnt(0) + per-wave flag.
__global__ __launch_bounds__(256, 1) void gru_layer(const ushort* __restrict__ W,
                                                    const float* __restrict__ bih,
                                                    const float* __restrict__ bhh,
                                                    const float* __restrict__ xp,
                                                    ushort* __restrict__ hseq,
                                                    float* __restrict__ hstate,
                                                    int* __restrict__ flags,
                                                    int t0, int tEnd) {
  __shared__ float P[2][4][24][64];   // [buf][wave][elem][lane], 48 KB
  const int tid = threadIdx.x;
  const int wv = tid >> 6, lane = tid & 63;
  const int fr = lane & 15, fq = lane >> 4;
  const int c0 = blockIdx.x << 4;
  const int c = c0 + fr;

  // W fragments into registers (one-time): wf[g][kk] = W[g*H + c][wv*256 + kk*32 + fq*8 ..+8]
  short8 wf[3][8];
#pragma unroll
  for (int g = 0; g < 3; ++g)
#pragma unroll
    for (int kk = 0; kk < 8; ++kk)
      wf[g][kk] = *(const short8*)&W[(size_t)(g * HH + c) * HH + wv * 256 + kk * 32 + fq * 8];

  float bhr = 0, bhz = 0, bhn = 0, bir = 0, biz = 0, bin_ = 0;
  float hl[4] = {0.f, 0.f, 0.f, 0.f};
  if (wv < 2) {
    bhr = bhh[c]; bhz = bhh[HH + c]; bhn = bhh[2 * HH + c];
    bir = bih[c]; biz = bih[HH + c]; bin_ = bih[2 * HH + c];
    if (t0 > 0) {
#pragma unroll
      for (int r = 0; r < 4; ++r)
        hl[r] = hstate[(wv * 16 + (fq << 2) + r) * HH + c];
    }
  }

  for (int t = t0; t < tEnd; ++t) {
    const int lt = t - t0;
    // prefetch gate inputs (stable memory) before the poll so latency overlaps the wait
    float xr[4], xz[4], xn[4];
    if (wv < 2) {
      const float* xpt = xp + (size_t)lt * (BB * 3 * HH);
#pragma unroll
      for (int r = 0; r < 4; ++r) {
        const float* p = xpt + (size_t)(wv * 16 + (fq << 2) + r) * (3 * HH) + c;
        xr[r] = p[0]; xz[r] = p[HH]; xn[r] = p[2 * HH];
      }
    }
    asm volatile("" ::: "memory");

    if (t > t0) {   // wait until all WGs published h[t] (both half-flags)
      int v;
      do {
        int v0 = __hip_atomic_load(flags + lane, __ATOMIC_RELAXED, __HIP_MEMORY_SCOPE_AGENT);
        int v1 = __hip_atomic_load(flags + 64 + lane, __ATOMIC_RELAXED, __HIP_MEMORY_SCOPE_AGENT);
        v = v0 < v1 ? v0 : v1;
        if (v < t) __builtin_amdgcn_s_sleep(1);
      } while (__any(v < t));
    }
    asm volatile("" ::: "memory");

    // A-fragments straight from global (first-touch lines -> L3 hit)
    const ushort* hb = hseq + (size_t)lt * (BB * HH) + (size_t)fr * HH + wv * 256 + (fq << 3);
    short8 a0[8], a1[8];
#pragma unroll
    for (int j = 0; j < 8; ++j) {
      a0[j] = *(const short8*)(hb + j * 32);
      a1[j] = *(const short8*)(hb + 16 * HH + j * 32);
    }
    f32x4 acc[2][3] = {};
#pragma unroll
    for (int j = 0; j < 8; ++j) {
      acc[0][0] = MFMA16(a0[j], wf[0][j], acc[0][0]);
      acc[0][1] = MFMA16(a0[j], wf[1][j], acc[0][1]);
      acc[0][2] = MFMA16(a0[j], wf[2][j], acc[0][2]);
      acc[1][0] = MFMA16(a1[j], wf[0][j], acc[1][0]);
      acc[1][1] = MFMA16(a1[j], wf[1][j], acc[1][1]);
      acc[1][2] = MFMA16(a1[j], wf[2][j], acc[1][2]);
    }

    const int pb = t & 1;
#pragma unroll
    for (int mt = 0; mt < 2; ++mt)
#pragma unroll
      for (int g = 0; g < 3; ++g)
#pragma unroll
        for (int r = 0; r < 4; ++r)
          P[pb][wv][mt * 12 + g * 4 + r][lane] = acc[mt][g][r];
    __syncthreads();

    if (wv < 2) {
      // reduce 4 K-partials for this wave's batch half (mt = wv)
      float s[3][4];
#pragma unroll
      for (int g = 0; g < 3; ++g)
#pragma unroll
        for (int r = 0; r < 4; ++r) {
          int e = wv * 12 + g * 4 + r;
          s[g][r] = P[pb][0][e][lane] + P[pb][1][e][lane] +
                    P[pb][2][e][lane] + P[pb][3][e][lane];
        }
      ushort* hw = hseq + (size_t)(lt + 1) * (BB * HH);
      const int cpair = c0 + (fr & ~1);
#pragma unroll
      for (int r = 0; r < 4; ++r) {
        float rv = 1.f / (1.f + __expf(-(xr[r] + bir + s[0][r] + bhr)));
        float zv = 1.f / (1.f + __expf(-(xz[r] + biz + s[1][r] + bhz)));
        float nv = tanhf(xn[r] + bin_ + rv * (s[2][r] + bhn));
        float h = (1.f - zv) * nv + zv * hl[r];
        hl[r] = h;
        unsigned me = f2b(h);
        unsigned nb = (unsigned)__shfl_xor((int)me, 1);
        unsigned word = me | (nb << 16);   // valid on even lanes
        int b = wv * 16 + (fq << 2) + r;
        if ((lane & 1) == 0)
          __hip_atomic_store((unsigned*)(hw + (size_t)b * HH + cpair), word,
                             __ATOMIC_RELAXED, __HIP_MEMORY_SCOPE_AGENT);
        if (t == tEnd - 1) {
          hstate[b * HH + c] = h;                                   // fp32 carry
          if ((lane & 1) == 0)
            *(unsigned*)(hseq + (size_t)b * HH + cpair) = word;     // slot 0 for next launch
        }
      }
      asm volatile("s_waitcnt vmcnt(0)" ::: "memory");   // h-stores acked at L3
      if (lane == 0)
        __hip_atomic_store(flags + wv * 64 + blockIdx.x, t + 1,
                           __ATOMIC_RELAXED, __HIP_MEMORY_SCOPE_AGENT);
    }
  }
}

// ---------------------------------------------------------------- final FC
__global__ __launch_bounds__(256) void fc_k(const float* __restrict__ h,
                                            const float* __restrict__ Wf,
                                            const float* __restrict__ bf,
                                            float* __restrict__ out) {
  int idx = blockIdx.x * 256 + threadIdx.x;   // grid 64 -> 16384 = 32x512
  int b = idx >> 9, o = idx & 511;
  const float4* hv = (const float4*)(h + (b << 10));
  const float4* wv = (const float4*)(Wf + (o << 10));
  float s = 0.f;
#pragma unroll 8
  for (int i = 0; i < 256; ++i) {
    float4 x = hv[i], y = wv[i];
    s += x.x * y.x + x.y * y.y + x.z * y.z + x.w * y.w;
  }
  out[idx] = s + bf[o];
}

// ---------------------------------------------------------------- launch
extern "C" void kernel_launch(void* const* d_in, const int* in_sizes, int n_in,
                              void* d_out, int out_size, void* d_ws, size_t ws_size,
                              hipStream_t stream) {
  const float* x    = (const float*)d_in[0];
  const float* Wih0 = (const float*)d_in[1];
  const float* Whh0 = (const float*)d_in[2];
  const float* bih0 = (const float*)d_in[3];
  const float* bhh0 = (const float*)d_in[4];
  const float* Wih1 = (const float*)d_in[5];
  const float* Whh1 = (const float*)d_in[6];
  const float* bih1 = (const float*)d_in[7];
  const float* bhh1 = (const float*)d_in[8];
  const float* Wfc  = (const float*)d_in[9];
  const float* bfc  = (const float*)d_in[10];
  float* out = (float*)d_out;

  // workspace layout (total ~89.6 MiB)
  char* w = (char*)d_ws;
  ushort* wi0b = (ushort*)(w);                    //  3,145,728
  ushort* wh0b = (ushort*)(w + 3145728);          //  6,291,456
  ushort* wi1b = (ushort*)(w + 9437184);          //  6,291,456
  ushort* wh1b = (ushort*)(w + 15728640);         //  6,291,456
  float*  xp   = (float*)(w + 22020096);          // 50,331,648  [128,B,3H] fp32
  ushort* h1   = (ushort*)(w + 72351744);         //  8,454,144  129 slots bf16
  ushort* h2   = (ushort*)(w + 80805888);         //  8,454,144  129 slots
  float*  hs0  = (float*)(w + 89260032);          //    131,072
  float*  hs1  = (float*)(w + 89391104);          //    131,072
  int*    flg0 = (int*)(w + 89522176);            //        512 (128 ints)
  int*    flg1 = (int*)(w + 89522688);            //        512

  init_k<<<128, 256, 0, stream>>>((unsigned int*)h1, (unsigned int*)h2, flg0, flg1);

  cast_k<<<1536, 256, 0, stream>>>(Wih0, wi0b, (3 * HH * DIN) / 4);
  cast_k<<<3072, 256, 0, stream>>>(Whh0, wh0b, (3 * HH * HH) / 4);
  cast_k<<<3072, 256, 0, stream>>>(Wih1, wi1b, (3 * HH * HH) / 4);
  cast_k<<<3072, 256, 0, stream>>>(Whh1, wh1b, (3 * HH * HH) / 4);

  for (int ch = 0; ch < 4; ++ch) {
    const int t0 = ch * CHUNK, t1 = (ch + 1) * CHUNK;
    gemm_bt<1><<<dim3(24, 32), 256, 0, stream>>>(x, wi0b, xp, 3 * HH, DIN, t0);
    gru_layer<<<64, 256, 0, stream>>>(wh0b, bih0, bhh0, xp, h1, hs0, flg0, t0, t1);
    gemm_bt<0><<<dim3(24, 32), 256, 0, stream>>>(h1 + 32768, wi1b, xp, 3 * HH, HH, 0);
    gru_layer<<<64, 256, 0, stream>>>(wh1b, bih1, bhh1, xp, h2, hs1, flg1, t0, t1);
  }

  fc_k<<<64, 256, 0, stream>>>(hs1, Wfc, bfc, out);
}

// Round 5
// 3931.370 us; speedup vs baseline: 1.9968x; 1.9968x over previous
//
#include <hip/hip_runtime.h>

typedef unsigned short ushort;
typedef __attribute__((ext_vector_type(8))) short short8;
typedef __attribute__((ext_vector_type(4))) float f32x4;
typedef __attribute__((ext_vector_type(4))) unsigned short us4;
typedef __attribute__((ext_vector_type(4))) unsigned int u32x4;

// Problem constants
#define BB 32
#define TT 512
#define DIN 512
#define HH 1024
#define CHUNK 128
#define SENT 0xFFFFFFFFu

__device__ __forceinline__ ushort f2b(float f) {
  unsigned u = __builtin_bit_cast(unsigned, f);
  unsigned r = (u + 0x7fffu + ((u >> 16) & 1u)) >> 16;
  return (ushort)r;
}

#define MFMA16(a, b, c) __builtin_amdgcn_mfma_f32_16x16x32_bf16(a, b, c, 0, 0, 0)

__device__ __forceinline__ void AS(unsigned* p, unsigned v) {
  __hip_atomic_store(p, v, __ATOMIC_RELAXED, __HIP_MEMORY_SCOPE_AGENT);
}

__device__ __forceinline__ bool fok(const u32x4& v) {
  return v[0] != SENT && v[1] != SENT && v[2] != SENT && v[3] != SENT;
}

// Poll NF=8 fragments (rowbase + j*32 ushorts) until none contains the sentinel.
__device__ __forceinline__ void poll8(const ushort* b, short8* f) {
  u32x4 t0, t1, t2, t3, t4, t5, t6, t7;
  while (true) {
    asm volatile(
        "global_load_dwordx4 %0, %8, off sc0 sc1\n\t"
        "global_load_dwordx4 %1, %9, off sc0 sc1\n\t"
        "global_load_dwordx4 %2, %10, off sc0 sc1\n\t"
        "global_load_dwordx4 %3, %11, off sc0 sc1\n\t"
        "global_load_dwordx4 %4, %12, off sc0 sc1\n\t"
        "global_load_dwordx4 %5, %13, off sc0 sc1\n\t"
        "global_load_dwordx4 %6, %14, off sc0 sc1\n\t"
        "global_load_dwordx4 %7, %15, off sc0 sc1\n\t"
        "s_waitcnt vmcnt(0)"
        : "=&v"(t0), "=&v"(t1), "=&v"(t2), "=&v"(t3),
          "=&v"(t4), "=&v"(t5), "=&v"(t6), "=&v"(t7)
        : "v"(b), "v"(b + 32), "v"(b + 64), "v"(b + 96),
          "v"(b + 128), "v"(b + 160), "v"(b + 192), "v"(b + 224)
        : "memory");
    bool ok = fok(t0) && fok(t1) && fok(t2) && fok(t3) &&
              fok(t4) && fok(t5) && fok(t6) && fok(t7);
    if (__all((int)ok)) break;
    __builtin_amdgcn_s_sleep(1);
  }
  f[0] = __builtin_bit_cast(short8, t0); f[1] = __builtin_bit_cast(short8, t1);
  f[2] = __builtin_bit_cast(short8, t2); f[3] = __builtin_bit_cast(short8, t3);
  f[4] = __builtin_bit_cast(short8, t4); f[5] = __builtin_bit_cast(short8, t5);
  f[6] = __builtin_bit_cast(short8, t6); f[7] = __builtin_bit_cast(short8, t7);
}

__device__ __forceinline__ void poll4(const ushort* b, short8* f) {
  u32x4 t0, t1, t2, t3;
  while (true) {
    asm volatile(
        "global_load_dwordx4 %0, %4, off sc0 sc1\n\t"
        "global_load_dwordx4 %1, %5, off sc0 sc1\n\t"
        "global_load_dwordx4 %2, %6, off sc0 sc1\n\t"
        "global_load_dwordx4 %3, %7, off sc0 sc1\n\t"
        "s_waitcnt vmcnt(0)"
        : "=&v"(t0), "=&v"(t1), "=&v"(t2), "=&v"(t3)
        : "v"(b), "v"(b + 32), "v"(b + 64), "v"(b + 96)
        : "memory");
    bool ok = fok(t0) && fok(t1) && fok(t2) && fok(t3);
    if (__all((int)ok)) break;
    __builtin_amdgcn_s_sleep(1);
  }
  f[0] = __builtin_bit_cast(short8, t0); f[1] = __builtin_bit_cast(short8, t1);
  f[2] = __builtin_bit_cast(short8, t2); f[3] = __builtin_bit_cast(short8, t3);
}

// ---------------------------------------------------------------- init / refill
__global__ __launch_bounds__(256) void init_k(unsigned int* h1s, unsigned int* h2s) {
  int i = blockIdx.x * 256 + threadIdx.x;   // grid 128 -> 32768
  if (i < 16384) h1s[i] = 0u;               // h1 slot 0
  else h2s[i - 16384] = 0u;                 // h2 slot 0
}

__global__ __launch_bounds__(256) void refill_k(u32x4* a, u32x4* b) {
  size_t i = (size_t)blockIdx.x * 256 + threadIdx.x;   // grid 2048 -> 524288
  u32x4 s = {SENT, SENT, SENT, SENT};
  a[i] = s;   // h1 slots 1..128
  b[i] = s;   // h2 slots 1..128
}

// ---------------------------------------------------------------- fp32 -> bf16 cast
__global__ __launch_bounds__(256) void cast_k(const float* __restrict__ in,
                                              ushort* __restrict__ out, int n4) {
  int i = blockIdx.x * 256 + threadIdx.x;
  if (i < n4) {
    float4 v = ((const float4*)in)[i];
    us4 o;
    o.x = f2b(v.x); o.y = f2b(v.y); o.z = f2b(v.z); o.w = f2b(v.w);
    ((us4*)out)[i] = o;
  }
}

// ---------------------------------------------------------------- bf16 GEMM  C = A @ B^T
// A = fp32 x [B,T,DIN] (cast on the fly), row m -> x[(m&31)*TT + tOff + (m>>5)].
__global__ __launch_bounds__(256) void gemm_bt(const float* __restrict__ A32,
                                               const ushort* __restrict__ B,
                                               float* __restrict__ C,
                                               int N, int K, int tOff) {
  __shared__ __align__(16) ushort As[128 * 72];
  __shared__ __align__(16) ushort Bs[128 * 72];
  const int tid = threadIdx.x;
  const int lane = tid & 63, wave = tid >> 6;
  const int wm = wave >> 1, wn = wave & 1;
  const int bm = blockIdx.y << 7, bn = blockIdx.x << 7;

  const int srow = tid >> 3;
  const int sdst = (tid & 7) << 3;
  size_t aoff[4], boff[4];
#pragma unroll
  for (int i = 0; i < 4; ++i) {
    int m = bm + srow + (i << 5);
    aoff[i] = ((size_t)(m & 31) * TT + tOff + (m >> 5)) * (size_t)K;
    boff[i] = (size_t)(bn + srow + (i << 5)) * K;
  }

  const int fr = lane & 15, fq = lane >> 4;
  int aofl[4], bofl[4];
#pragma unroll
  for (int m = 0; m < 4; ++m) {
    aofl[m] = ((wm << 6) + (m << 4) + fr) * 72 + (fq << 3);
    bofl[m] = ((wn << 6) + (m << 4) + fr) * 72 + (fq << 3);
  }

  f32x4 acc[4][4] = {};
  for (int k0 = 0; k0 < K; k0 += 64) {
#pragma unroll
    for (int i = 0; i < 4; ++i) {
      int row = srow + (i << 5);
      float4 v0 = *(const float4*)&A32[aoff[i] + k0 + sdst];
      float4 v1 = *(const float4*)&A32[aoff[i] + k0 + sdst + 4];
      us4 lo, hi;
      lo.x = f2b(v0.x); lo.y = f2b(v0.y); lo.z = f2b(v0.z); lo.w = f2b(v0.w);
      hi.x = f2b(v1.x); hi.y = f2b(v1.y); hi.z = f2b(v1.z); hi.w = f2b(v1.w);
      *(us4*)&As[row * 72 + sdst] = lo;
      *(us4*)&As[row * 72 + sdst + 4] = hi;
      *(short8*)&Bs[row * 72 + sdst] = *(const short8*)&B[boff[i] + k0 + sdst];
    }
    __syncthreads();
#pragma unroll
    for (int kk = 0; kk < 2; ++kk) {
      short8 af[4], bf[4];
#pragma unroll
      for (int m = 0; m < 4; ++m) af[m] = *(const short8*)&As[aofl[m] + kk * 32];
#pragma unroll
      for (int n = 0; n < 4; ++n) bf[n] = *(const short8*)&Bs[bofl[n] + kk * 32];
#pragma unroll
      for (int m = 0; m < 4; ++m)
#pragma unroll
        for (int n = 0; n < 4; ++n)
          acc[m][n] = MFMA16(af[m], bf[n], acc[m][n]);
    }
    __syncthreads();
  }
#pragma unroll
  for (int m = 0; m < 4; ++m) {
    int row0 = bm + (wm << 6) + (m << 4) + (fq << 2);
#pragma unroll
    for (int n = 0; n < 4; ++n) {
      int col = bn + (wn << 6) + (n << 4) + fr;
#pragma unroll
      for (int r = 0; r < 4; ++r)
        C[(size_t)(row0 + r) * N + col] = acc[m][n][r];
    }
  }
}

// ---------------------------------------------------------------- fused 2-layer GRU
// 128 WGs x 512 thr. WGs 0..63: layer 0 (xp precomputed). WGs 64..127: layer 1,
// one step behind, computing Wih1@h1out on the fly. Sentinel-based dataflow sync:
// producers fire agent-scope stores; consumers poll their own fragments with
// coherent loads until no dword equals SENT.
__global__ __launch_bounds__(512, 1) void gru_fused(
    const ushort* __restrict__ wh0, const ushort* __restrict__ wh1,
    const ushort* __restrict__ wi1,
    const float* __restrict__ bih0, const float* __restrict__ bhh0,
    const float* __restrict__ bih1, const float* __restrict__ bhh1,
    const float* __restrict__ xp,
    ushort* __restrict__ h1, ushort* __restrict__ h2,
    float* __restrict__ hs0, float* __restrict__ hs1,
    int t0, int nSteps) {
  __shared__ float P[8][24][64];   // 48 KB partials
  const int tid = threadIdx.x;
  const int wv = tid >> 6, lane = tid & 63;
  const int fr = lane & 15, fq = lane >> 4;
  const int layer = blockIdx.x >> 6;
  const int c0 = (blockIdx.x & 63) << 4;
  const int c = c0 + fr;
  const int cpair = c0 + (fr & ~1);

  if (layer == 0) {
    // ---------------- layer 0 ----------------
    const int K0 = wv << 7;   // K in [128*wv, 128*wv+128)
    short8 wf[3][4];
#pragma unroll
    for (int g = 0; g < 3; ++g)
#pragma unroll
      for (int j = 0; j < 4; ++j)
        wf[g][j] = *(const short8*)&wh0[(size_t)(g * HH + c) * HH + K0 + j * 32 + fq * 8];

    float bhr = 0, bhz = 0, bhn = 0, bir = 0, biz = 0, bin_ = 0;
    float hl[4] = {};
    if (wv < 2) {
      bhr = bhh0[c]; bhz = bhh0[HH + c]; bhn = bhh0[2 * HH + c];
      bir = bih0[c]; biz = bih0[HH + c]; bin_ = bih0[2 * HH + c];
      if (t0 > 0)
#pragma unroll
        for (int r = 0; r < 4; ++r) hl[r] = hs0[(wv * 16 + (fq << 2) + r) * HH + c];
    }

    for (int i = 0; i < nSteps; ++i) {
      float xr[4], xz[4], xn[4];
      if (wv < 2) {
        const float* xpt = xp + (size_t)i * (BB * 3 * HH);
#pragma unroll
        for (int r = 0; r < 4; ++r) {
          const float* p = xpt + (size_t)(wv * 16 + (fq << 2) + r) * (3 * HH) + c;
          xr[r] = p[0]; xz[r] = p[HH]; xn[r] = p[2 * HH];
        }
      }
      const ushort* sb = h1 + (size_t)i * (BB * HH);
      short8 a0[4], a1[4];
      poll4(sb + fr * HH + K0 + fq * 8, a0);
      poll4(sb + (fr + 16) * HH + K0 + fq * 8, a1);
      f32x4 acc[2][3] = {};
#pragma unroll
      for (int j = 0; j < 4; ++j) {
        acc[0][0] = MFMA16(a0[j], wf[0][j], acc[0][0]);
        acc[0][1] = MFMA16(a0[j], wf[1][j], acc[0][1]);
        acc[0][2] = MFMA16(a0[j], wf[2][j], acc[0][2]);
        acc[1][0] = MFMA16(a1[j], wf[0][j], acc[1][0]);
        acc[1][1] = MFMA16(a1[j], wf[1][j], acc[1][1]);
        acc[1][2] = MFMA16(a1[j], wf[2][j], acc[1][2]);
      }
#pragma unroll
      for (int mt = 0; mt < 2; ++mt)
#pragma unroll
        for (int g = 0; g < 3; ++g)
#pragma unroll
          for (int r = 0; r < 4; ++r)
            P[wv][mt * 12 + g * 4 + r][lane] = acc[mt][g][r];
      __syncthreads();

      if (wv < 2) {
        float s[3][4];
#pragma unroll
        for (int g = 0; g < 3; ++g)
#pragma unroll
          for (int r = 0; r < 4; ++r) {
            int e = wv * 12 + g * 4 + r;
            float v = 0.f;
#pragma unroll
            for (int w = 0; w < 8; ++w) v += P[w][e][lane];
            s[g][r] = v;
          }
        ushort* hw = h1 + (size_t)(i + 1) * (BB * HH);
        const bool last = (i == nSteps - 1);
#pragma unroll
        for (int r = 0; r < 4; ++r) {
          float rv = 1.f / (1.f + __expf(-(xr[r] + bir + s[0][r] + bhr)));
          float zv = 1.f / (1.f + __expf(-(xz[r] + biz + s[1][r] + bhz)));
          float nv = tanhf(xn[r] + bin_ + rv * (s[2][r] + bhn));
          float h = (1.f - zv) * nv + zv * hl[r];
          hl[r] = h;
          unsigned me = f2b(h);
          unsigned nb = (unsigned)__shfl_xor((int)me, 1);
          unsigned word = me | (nb << 16);   // valid on even lanes
          int b = wv * 16 + (fq << 2) + r;
          if ((lane & 1) == 0)
            AS((unsigned*)(hw + (size_t)b * HH + cpair), word);
          if (last) {
            hs0[b * HH + c] = h;
            if ((lane & 1) == 0)
              *(unsigned*)(h1 + (size_t)b * HH + cpair) = word;   // slot 0, next launch
          }
        }
      }
      __syncthreads();
    }
  } else {
    // ---------------- layer 1 ----------------
    const int K0 = (wv & 3) << 8;   // K in [256*(wv&3), +256)
    const ushort* Wm = (wv < 4) ? wh1 : wi1;
    short8 wf[3][8];
#pragma unroll
    for (int g = 0; g < 3; ++g)
#pragma unroll
      for (int j = 0; j < 8; ++j)
        wf[g][j] = *(const short8*)&Wm[(size_t)(g * HH + c) * HH + K0 + j * 32 + fq * 8];

    float bhr = 0, bhz = 0, bhn = 0, bir = 0, biz = 0, bin_ = 0;
    float hl[4] = {};
    if (wv < 2) {
      bhr = bhh1[c]; bhz = bhh1[HH + c]; bhn = bhh1[2 * HH + c];
      bir = bih1[c]; biz = bih1[HH + c]; bin_ = bih1[2 * HH + c];
      if (t0 > 0)
#pragma unroll
        for (int r = 0; r < 4; ++r) hl[r] = hs1[(wv * 16 + (fq << 2) + r) * HH + c];
    }

    for (int i = 0; i < nSteps; ++i) {
      // waves 0-3: h2[t] (own state); waves 4-7: h1out[t] = h1 slot i+1
      const ushort* sb = (wv < 4) ? h2 + (size_t)i * (BB * HH)
                                  : h1 + (size_t)(i + 1) * (BB * HH);
      short8 a0[8], a1[8];
      poll8(sb + fr * HH + K0 + fq * 8, a0);
      f32x4 acc[2][3] = {};
#pragma unroll
      for (int j = 0; j < 8; ++j) {
        acc[0][0] = MFMA16(a0[j], wf[0][j], acc[0][0]);
        acc[0][1] = MFMA16(a0[j], wf[1][j], acc[0][1]);
        acc[0][2] = MFMA16(a0[j], wf[2][j], acc[0][2]);
      }
      poll8(sb + (fr + 16) * HH + K0 + fq * 8, a1);
#pragma unroll
      for (int j = 0; j < 8; ++j) {
        acc[1][0] = MFMA16(a1[j], wf[0][j], acc[1][0]);
        acc[1][1] = MFMA16(a1[j], wf[1][j], acc[1][1]);
        acc[1][2] = MFMA16(a1[j], wf[2][j], acc[1][2]);
      }
#pragma unroll
      for (int mt = 0; mt < 2; ++mt)
#pragma unroll
        for (int g = 0; g < 3; ++g)
#pragma unroll
          for (int r = 0; r < 4; ++r)
            P[wv][mt * 12 + g * 4 + r][lane] = acc[mt][g][r];
      __syncthreads();

      if (wv < 2) {
        float sh[3][4], sx[3][4];
#pragma unroll
        for (int g = 0; g < 3; ++g)
#pragma unroll
          for (int r = 0; r < 4; ++r) {
            int e = wv * 12 + g * 4 + r;
            float vh = 0.f, vx = 0.f;
#pragma unroll
            for (int w = 0; w < 4; ++w) vh += P[w][e][lane];
#pragma unroll
            for (int w = 4; w < 8; ++w) vx += P[w][e][lane];
            sh[g][r] = vh; sx[g][r] = vx;
          }
        ushort* hw = h2 + (size_t)(i + 1) * (BB * HH);
        const bool last = (i == nSteps - 1);
#pragma unroll
        for (int r = 0; r < 4; ++r) {
          float rv = 1.f / (1.f + __expf(-(sx[0][r] + bir + sh[0][r] + bhr)));
          float zv = 1.f / (1.f + __expf(-(sx[1][r] + biz + sh[1][r] + bhz)));
          float nv = tanhf(sx[2][r] + bin_ + rv * (sh[2][r] + bhn));
          float h = (1.f - zv) * nv + zv * hl[r];
          hl[r] = h;
          unsigned me = f2b(h);
          unsigned nb = (unsigned)__shfl_xor((int)me, 1);
          unsigned word = me | (nb << 16);
          int b = wv * 16 + (fq << 2) + r;
          if (!last) {
            if ((lane & 1) == 0)
              AS((unsigned*)(hw + (size_t)b * HH + cpair), word);
          } else {
            hs1[b * HH + c] = h;
            if ((lane & 1) == 0)
              *(unsigned*)(h2 + (size_t)b * HH + cpair) = word;   // slot 0, next launch
          }
        }
      }
      __syncthreads();
    }
  }
}

// ---------------------------------------------------------------- final FC
__global__ __launch_bounds__(256) void fc_k(const float* __restrict__ h,
                                            const float* __restrict__ Wf,
                                            const float* __restrict__ bf,
                                            float* __restrict__ out) {
  int idx = blockIdx.x * 256 + threadIdx.x;   // grid 64 -> 16384 = 32x512
  int b = idx >> 9, o = idx & 511;
  const float4* hv = (const float4*)(h + (b << 10));
  const float4* wv = (const float4*)(Wf + (o << 10));
  float s = 0.f;
#pragma unroll 8
  for (int i = 0; i < 256; ++i) {
    float4 x = hv[i], y = wv[i];
    s += x.x * y.x + x.y * y.y + x.z * y.z + x.w * y.w;
  }
  out[idx] = s + bf[o];
}

// ---------------------------------------------------------------- launch
extern "C" void kernel_launch(void* const* d_in, const int* in_sizes, int n_in,
                              void* d_out, int out_size, void* d_ws, size_t ws_size,
                              hipStream_t stream) {
  const float* x    = (const float*)d_in[0];
  const float* Wih0 = (const float*)d_in[1];
  const float* Whh0 = (const float*)d_in[2];
  const float* bih0 = (const float*)d_in[3];
  const float* bhh0 = (const float*)d_in[4];
  const float* Wih1 = (const float*)d_in[5];
  const float* Whh1 = (const float*)d_in[6];
  const float* bih1 = (const float*)d_in[7];
  const float* bhh1 = (const float*)d_in[8];
  const float* Wfc  = (const float*)d_in[9];
  const float* bfc  = (const float*)d_in[10];
  float* out = (float*)d_out;

  // workspace layout (total ~89.5 MiB)
  char* w = (char*)d_ws;
  ushort* wi0b = (ushort*)(w);                    //  3,145,728
  ushort* wh0b = (ushort*)(w + 3145728);          //  6,291,456
  ushort* wi1b = (ushort*)(w + 9437184);          //  6,291,456
  ushort* wh1b = (ushort*)(w + 15728640);         //  6,291,456
  float*  xp   = (float*)(w + 22020096);          // 50,331,648  [128,B,3H] fp32
  ushort* h1   = (ushort*)(w + 72351744);         //  8,454,144  129 slots bf16
  ushort* h2   = (ushort*)(w + 80805888);         //  8,454,144  129 slots
  float*  hs0  = (float*)(w + 89260032);          //    131,072
  float*  hs1  = (float*)(w + 89391104);          //    131,072

  init_k<<<128, 256, 0, stream>>>((unsigned int*)h1, (unsigned int*)h2);

  cast_k<<<1536, 256, 0, stream>>>(Wih0, wi0b, (3 * HH * DIN) / 4);
  cast_k<<<3072, 256, 0, stream>>>(Whh0, wh0b, (3 * HH * HH) / 4);
  cast_k<<<3072, 256, 0, stream>>>(Wih1, wi1b, (3 * HH * HH) / 4);
  cast_k<<<3072, 256, 0, stream>>>(Whh1, wh1b, (3 * HH * HH) / 4);

  for (int ch = 0; ch < 4; ++ch) {
    const int t0 = ch * CHUNK;
    gemm_bt<<<dim3(24, 32), 256, 0, stream>>>(x, wi0b, xp, 3 * HH, DIN, t0);
    refill_k<<<2048, 256, 0, stream>>>((u32x4*)(h1 + BB * HH), (u32x4*)(h2 + BB * HH));
    gru_fused<<<128, 512, 0, stream>>>(wh0b, wh1b, wi1b, bih0, bhh0, bih1, bhh1,
                                       xp, h1, h2, hs0, hs1, t0, CHUNK);
  }

  fc_k<<<64, 256, 0, stream>>>(hs1, Wfc, bfc, out);
}